// Round 6
// baseline (24718.622 us; speedup 1.0000x reference)
//
#include <hip/hip_runtime.h>
#include <hip/hip_bf16.h>

// BiLSTM(512/dir, T=8192) + linear(9) + Viterbi decode.
//  K1 gemm_xproj : 128x128 tile, 8x8 register blocking (VALU fp32; no fp32 MFMA on CDNA4)
//  K2 lstm_scan  : 64 persistent blocks (32/dir) x 256 threads, SINGLE-STAGE waves:
//                  each wave owns 4 h values end-to-end (16 rows x 512 k, 128 w/lane).
//                  No barriers, no cross-wave sync. Each lane polls 4 u64 of h(t-1)
//                  (256 u64 = full 512-float h per wave), stages into bank-padded
//                  wave-private LDS (chunk stride 132), dot + shfl reduce + gates
//                  in-wave, u64 store of the 4 h values.
//  K3 feats      : feats[t,n] = [h_f|h_b] @ W_out^T + b_out
//  K4 viterbi    : single wave; backpointers packed 4b x 9 into u64/step.
//
// ws layout (floats):
//   [0)                 xprojb   8192*4096            = 128 MB
//   [+8192*4096)        h_seq    2*8192*512           =  32 MB (poisoned 0x7F each launch)
//   [+2*8192*512)       feats    8192*9
//   [then]              bpw      8192 u64

#define T_SEQ   8192
#define EMB     512
#define HDIM    512
#define POISON64 0x7F7F7F7F7F7F7F7Full  // |h|<1 so never produced

#define ALOAD(p)  __hip_atomic_load((p), __ATOMIC_RELAXED, __HIP_MEMORY_SCOPE_AGENT)

// ---------------------------------------------------------------- K1: GEMM
__global__ __launch_bounds__(256) void gemm_xproj(
    const int* __restrict__ sentence, const float* __restrict__ emb,
    const float* __restrict__ Wih_f, const float* __restrict__ Wih_b,
    const float* __restrict__ bih_f, const float* __restrict__ bhh_f,
    const float* __restrict__ bih_b, const float* __restrict__ bhh_b,
    float* __restrict__ xprojb)
{
    __shared__ float As[16][132];      // [kk][row], pad to 132 floats
    __shared__ float Bs[16][132];
    __shared__ int   srow[128];

    const int tid = threadIdx.x;
    const int bm = blockIdx.x;          // 64 tiles of 128 t
    const int bn = blockIdx.y;          // 32 tiles of 128 j (0..15 fwd, 16..31 bwd)
    const int fwd = (bn < 16);
    const float* __restrict__ W = fwd ? Wih_f : Wih_b;
    const int jbase = bn * 128 - (fwd ? 0 : 2048);

    if (tid < 128) srow[tid] = sentence[bm * 128 + tid];
    __syncthreads();

    const int lkk = tid & 15;           // staging k index
    const int lr  = tid >> 4;           // staging row group (8 rows)
    int sr[8];
    #pragma unroll
    for (int i = 0; i < 8; ++i) sr[i] = srow[lr * 8 + i];
    const float* wbase = W + (size_t)(jbase + lr * 8) * EMB + lkk;

    const int tx = tid & 15, ty = tid >> 4;
    float acc[8][8] = {};

    for (int kb = 0; kb < 32; ++kb) {
        const int k0 = kb * 16;
        #pragma unroll
        for (int i = 0; i < 8; ++i) {
            As[lkk][lr * 8 + i] = emb[(size_t)sr[i] * EMB + k0 + lkk];
            Bs[lkk][lr * 8 + i] = wbase[(size_t)i * EMB + k0];
        }
        __syncthreads();
        #pragma unroll
        for (int kk = 0; kk < 16; ++kk) {
            const float4 a0 = *(const float4*)&As[kk][ty * 8];
            const float4 a1 = *(const float4*)&As[kk][ty * 8 + 4];
            const float4 b0 = *(const float4*)&Bs[kk][tx * 8];
            const float4 b1 = *(const float4*)&Bs[kk][tx * 8 + 4];
            const float av[8] = {a0.x,a0.y,a0.z,a0.w,a1.x,a1.y,a1.z,a1.w};
            const float bv[8] = {b0.x,b0.y,b0.z,b0.w,b1.x,b1.y,b1.z,b1.w};
            #pragma unroll
            for (int i = 0; i < 8; ++i)
                #pragma unroll
                for (int j = 0; j < 8; ++j)
                    acc[i][j] = fmaf(av[i], bv[j], acc[i][j]);
        }
        __syncthreads();
    }

    const float* b1p = fwd ? bih_f : bih_b;
    const float* b2p = fwd ? bhh_f : bhh_b;
    float bias[8];
    #pragma unroll
    for (int j = 0; j < 8; ++j) {
        const int jj = jbase + tx * 8 + j;
        bias[j] = b1p[jj] + b2p[jj];
    }
    #pragma unroll
    for (int i = 0; i < 8; ++i) {
        const int t = bm * 128 + ty * 8 + i;
        float4* dst = (float4*)&xprojb[(size_t)t * 4096 + bn * 128 + tx * 8];
        dst[0] = make_float4(acc[i][0] + bias[0], acc[i][1] + bias[1],
                             acc[i][2] + bias[2], acc[i][3] + bias[3]);
        dst[1] = make_float4(acc[i][4] + bias[4], acc[i][5] + bias[5],
                             acc[i][6] + bias[6], acc[i][7] + bias[7]);
    }
}

// ------------------------------------------------------------- K2: LSTM scan
__device__ __forceinline__ float fsig(float x) { return 1.0f / (1.0f + __expf(-x)); }
__device__ __forceinline__ float ftanh(float x) {
    const float e = __expf(-2.0f * fabsf(x));
    return copysignf((1.0f - e) / (1.0f + e), x);
}
__device__ __forceinline__ unsigned long long pack2(float a, float b) {
    return (unsigned long long)__float_as_uint(a) |
           ((unsigned long long)__float_as_uint(b) << 32);
}
__device__ __forceinline__ float2 unpack2(unsigned long long u) {
    return make_float2(__uint_as_float((unsigned)(u & 0xffffffffull)),
                       __uint_as_float((unsigned)(u >> 32)));
}

#define CH 132   // padded chunk stride (floats): banks (4*kq + 4*j) % 32 -> conflict-free

__global__ __launch_bounds__(256, 1) void lstm_scan(
    const float* __restrict__ xprojb,
    const float* __restrict__ Whh_f, const float* __restrict__ Whh_b,
    float* __restrict__ hseq)
{
    const int tid  = threadIdx.x;
    const int lane = tid & 63;
    const int wv   = tid >> 6;          // wave 0..3; wave owns h indices wv*4..wv*4+3
    const int blk  = blockIdx.x;        // 0..63
    const int dir  = blk & 1;
    const int sub  = blk >> 1;          // 0..31; block owns h[sub*16 .. sub*16+15]
    const float* __restrict__ Whh = dir ? Whh_b : Whh_f;
    float* hs = hseq + (size_t)dir * T_SEQ * HDIM;

    // lane -> (row r = gate*4 + jm, k-quarter kq)
    const int r    = lane >> 2;         // 0..15
    const int kq   = lane & 3;          // k in [kq*128, kq*128+128)
    const int gate = r >> 2;            // 0..3 (i,f,g,o)
    const int jm   = r & 3;             // block-local m offset within wave
    const int mloc = wv * 4 + jm;       // 0..15
    const int row  = gate * 512 + sub * 16 + mloc;

    // 128 weights per lane (register-resident)
    float wr[128];
    {
        const float* src = Whh + (size_t)row * 512 + kq * 128;
        #pragma unroll
        for (int i = 0; i < 32; ++i) {
            const float4 v = *(const float4*)(src + 4 * i);
            wr[4*i] = v.x; wr[4*i+1] = v.y; wr[4*i+2] = v.z; wr[4*i+3] = v.w;
        }
    }
    #pragma unroll
    for (int i = 0; i < 128; ++i) asm volatile("" : "+v"(wr[i]));

    __shared__ __align__(16) float hst[4][4 * CH];   // wave-private, bank-padded
    float* hbuf = hst[wv];

    const int  jj = (lane >> 2) & 3;              // j for gate lanes (0,4,8,12)
    const bool gl = ((lane & 3) == 0) && (lane < 16);
    float c_state = 0.0f;

    #pragma unroll 1
    for (int s = 0; s < T_SEQ; ++s) {
        const int t = dir ? (T_SEQ - 1 - s) : s;

        // xproj prefetch for gate lanes — hides under the poll
        float xp0 = 0.f, xp1 = 0.f, xp2 = 0.f, xp3 = 0.f;
        if (gl) {
            const float* xr = xprojb + (size_t)t * 4096 + dir * 2048 + sub * 16 + wv * 4 + jj;
            xp0 = xr[0]; xp1 = xr[512]; xp2 = xr[1024]; xp3 = xr[1536];
        }

        // poll the FULL h(t-1): 4 u64 per lane (8 floats), issued together so all
        // four are in flight concurrently; re-poll each until non-poison.
        float2 v0, v1, v2, v3;
        if (s == 0) {
            v0 = v1 = v2 = v3 = make_float2(0.f, 0.f);
        } else {
            const int tprev = dir ? (t + 1) : (t - 1);
            const unsigned long long* hp =
                (const unsigned long long*)(hs + (size_t)tprev * HDIM);
            unsigned long long u0 = ALOAD(hp + lane);
            unsigned long long u1 = ALOAD(hp + 64 + lane);
            unsigned long long u2 = ALOAD(hp + 128 + lane);
            unsigned long long u3 = ALOAD(hp + 192 + lane);
            while (u0 == POISON64) u0 = ALOAD(hp + lane);
            while (u1 == POISON64) u1 = ALOAD(hp + 64 + lane);
            while (u2 == POISON64) u2 = ALOAD(hp + 128 + lane);
            while (u3 == POISON64) u3 = ALOAD(hp + 192 + lane);
            v0 = unpack2(u0); v1 = unpack2(u1); v2 = unpack2(u2); v3 = unpack2(u3);
        }
        // stage: chunk i holds h[128i .. 128i+127] at hbuf[i*CH ..]; lane writes
        // float pair 2*lane of each chunk (2-way bank alias on writes = free)
        *(float2*)(hbuf + 0 * CH + 2 * lane) = v0;
        *(float2*)(hbuf + 1 * CH + 2 * lane) = v1;
        *(float2*)(hbuf + 2 * CH + 2 * lane) = v2;
        *(float2*)(hbuf + 3 * CH + 2 * lane) = v3;

        // dot: one row x 128 k per lane; 16-lane groups broadcast, kq groups in
        // disjoint banks thanks to the CH=132 pad.
        float acc = 0.f;
        const float4* h4 = (const float4*)(hbuf + kq * CH);
        #pragma unroll
        for (int i2 = 0; i2 < 32; ++i2) {
            const float4 hv = h4[i2];
            acc = fmaf(wr[4*i2],   hv.x, acc);
            acc = fmaf(wr[4*i2+1], hv.y, acc);
            acc = fmaf(wr[4*i2+2], hv.z, acc);
            acc = fmaf(wr[4*i2+3], hv.w, acc);
        }
        // sum the 4 k-quarters (lanes r*4 + {0..3})
        acc += __shfl_xor(acc, 1);
        acc += __shfl_xor(acc, 2);

        // gather the 4 gate sums for m=jj: row gate*4+jj lives at lane gate*16+jj*4
        const float si = __shfl(acc, jj * 4);
        const float sf = __shfl(acc, jj * 4 + 16);
        const float sg = __shfl(acc, jj * 4 + 32);
        const float so = __shfl(acc, jj * 4 + 48);

        float h = 0.f;
        if (gl) {
            const float i_ = fsig(si + xp0);
            const float f_ = fsig(sf + xp1);
            const float g_ = ftanh(sg + xp2);
            const float o_ = fsig(so + xp3);
            c_state = fmaf(f_, c_state, i_ * g_);
            h = o_ * ftanh(c_state);
        }
        // pack (h0,h1),(h2,h3) and publish as u64 (no tearing)
        const float ha = __shfl(h, lane * 8);       // lane0<-0, lane1<-8
        const float hb = __shfl(h, lane * 8 + 4);   // lane0<-4, lane1<-12
        if (lane < 2) {
            unsigned long long* hdst =
                (unsigned long long*)(hs + (size_t)t * HDIM + sub * 16 + wv * 4);
            __hip_atomic_store(hdst + lane, pack2(ha, hb), __ATOMIC_RELAXED,
                               __HIP_MEMORY_SCOPE_AGENT);
        }
    }
}

// ---------------------------------------------------------------- K3: feats
__global__ __launch_bounds__(256) void feats_kernel(
    const float* __restrict__ hseq, const float* __restrict__ W_out,
    const float* __restrict__ b_out, float* __restrict__ feats)
{
    const int idx = blockIdx.x * 256 + threadIdx.x;   // (t, n)
    if (idx >= T_SEQ * 9) return;
    const int t = idx / 9;
    const int n = idx - t * 9;
    const float4* hf = (const float4*)(hseq + (size_t)t * HDIM);
    const float4* hb = (const float4*)(hseq + (size_t)(T_SEQ + t) * HDIM);
    const float4* wf = (const float4*)(W_out + (size_t)n * 1024);
    const float4* wb = wf + 128;
    float acc = b_out[n];
    #pragma unroll 8
    for (int i = 0; i < 128; ++i) {
        const float4 a = hf[i], w = wf[i];
        acc = fmaf(a.x, w.x, acc); acc = fmaf(a.y, w.y, acc);
        acc = fmaf(a.z, w.z, acc); acc = fmaf(a.w, w.w, acc);
    }
    #pragma unroll 8
    for (int i = 0; i < 128; ++i) {
        const float4 a = hb[i], w = wb[i];
        acc = fmaf(a.x, w.x, acc); acc = fmaf(a.y, w.y, acc);
        acc = fmaf(a.z, w.z, acc); acc = fmaf(a.w, w.w, acc);
    }
    feats[idx] = acc;
}

// --------------------------------------------------------------- K4: viterbi
__global__ __launch_bounds__(64) void viterbi_kernel(
    const float* __restrict__ feats, const float* __restrict__ trans,
    unsigned long long* __restrict__ bpw, float* __restrict__ out)
{
    const int lane = threadIdx.x;
    __shared__ __align__(16) float flds[1024 * 9];
    __shared__ unsigned char path_lds[T_SEQ];

    float tr[9];
    #pragma unroll
    for (int p = 0; p < 9; ++p) tr[p] = 0.f;
    float tstop = 0.f;
    if (lane < 9) {
        #pragma unroll
        for (int p = 0; p < 9; ++p) tr[p] = trans[lane * 9 + p];
        tstop = trans[8 * 9 + lane];
    }
    float fv = (lane == 7) ? 0.0f : -10000.0f;        // START_IDX = 7

    for (int ch = 0; ch < 8; ++ch) {
        const float4* src = (const float4*)(feats + (size_t)ch * 9216);
        #pragma unroll
        for (int i = 0; i < 36; ++i)
            ((float4*)flds)[lane + i * 64] = src[lane + i * 64];
        __syncthreads();

        for (int tt = 0; tt < 1024; ++tt) {
            const int t = ch * 1024 + tt;
            const float f0 = __shfl(fv, 0), f1 = __shfl(fv, 1), f2 = __shfl(fv, 2);
            const float f3 = __shfl(fv, 3), f4 = __shfl(fv, 4), f5 = __shfl(fv, 5);
            const float f6 = __shfl(fv, 6), f7 = __shfl(fv, 7), f8 = __shfl(fv, 8);
            const float s0 = f0 + tr[0], s1 = f1 + tr[1], s2 = f2 + tr[2];
            const float s3 = f3 + tr[3], s4 = f4 + tr[4], s5 = f5 + tr[5];
            const float s6 = f6 + tr[6], s7 = f7 + tr[7], s8 = f8 + tr[8];
            const float mx = fmaxf(fmaxf(fmaxf(fmaxf(s0, s1), fmaxf(s2, s3)),
                                         fmaxf(fmaxf(s4, s5), fmaxf(s6, s7))), s8);
            const unsigned bits =
                (s0 >= mx ? 1u : 0u)   | (s1 >= mx ? 2u : 0u)   | (s2 >= mx ? 4u : 0u) |
                (s3 >= mx ? 8u : 0u)   | (s4 >= mx ? 16u : 0u)  | (s5 >= mx ? 32u : 0u) |
                (s6 >= mx ? 64u : 0u)  | (s7 >= mx ? 128u : 0u) | (s8 >= mx ? 256u : 0u);
            const int bi = __ffs(bits) - 1;
            const float feat = (lane < 9) ? flds[tt * 9 + lane] : 0.0f;
            fv = mx + feat;
            const unsigned long long b0 = __ballot(bi & 1);
            const unsigned long long b1 = __ballot(bi & 2);
            const unsigned long long b2 = __ballot(bi & 4);
            const unsigned long long b3 = __ballot(bi & 8);
            if (lane == 0) {
                bpw[t] = (b0 & 511ull) | ((b1 & 511ull) << 9) |
                         ((b2 & 511ull) << 18) | ((b3 & 511ull) << 27);
            }
        }
        __syncthreads();
    }

    const float term = fv + tstop;
    const float t0 = __shfl(term, 0), t1 = __shfl(term, 1), t2 = __shfl(term, 2);
    const float t3 = __shfl(term, 3), t4 = __shfl(term, 4), t5 = __shfl(term, 5);
    const float t6 = __shfl(term, 6), t7 = __shfl(term, 7), t8 = __shfl(term, 8);
    const float mxt = fmaxf(fmaxf(fmaxf(fmaxf(t0, t1), fmaxf(t2, t3)),
                                  fmaxf(fmaxf(t4, t5), fmaxf(t6, t7))), t8);
    const unsigned bitst =
        (t0 >= mxt ? 1u : 0u)   | (t1 >= mxt ? 2u : 0u)   | (t2 >= mxt ? 4u : 0u) |
        (t3 >= mxt ? 8u : 0u)   | (t4 >= mxt ? 16u : 0u)  | (t5 >= mxt ? 32u : 0u) |
        (t6 >= mxt ? 64u : 0u)  | (t7 >= mxt ? 128u : 0u) | (t8 >= mxt ? 256u : 0u);
    const int best = __ffs(bitst) - 1;

    if (lane == 0) {
        out[0] = mxt;
        int c = best;
        path_lds[T_SEQ - 1] = (unsigned char)c;
        for (int thi = T_SEQ - 2; thi >= 15; thi -= 16) {
            const int tlo = thi - 15;
            unsigned long long wbuf[16];
            #pragma unroll
            for (int i = 0; i < 16; ++i) wbuf[i] = bpw[tlo + 1 + i];
            #pragma unroll
            for (int i = 15; i >= 0; --i) {
                const unsigned long long wvv = wbuf[i];
                c = (int)((wvv >> c) & 1ull) |
                    ((int)((wvv >> (9 + c)) & 1ull) << 1) |
                    ((int)((wvv >> (18 + c)) & 1ull) << 2) |
                    ((int)((wvv >> (27 + c)) & 1ull) << 3);
                path_lds[tlo + i] = (unsigned char)c;
            }
        }
        for (int t2i = 14; t2i >= 0; --t2i) {
            const unsigned long long wvv = bpw[t2i + 1];
            c = (int)((wvv >> c) & 1ull) |
                ((int)((wvv >> (9 + c)) & 1ull) << 1) |
                ((int)((wvv >> (18 + c)) & 1ull) << 2) |
                ((int)((wvv >> (27 + c)) & 1ull) << 3);
            path_lds[t2i] = (unsigned char)c;
        }
    }
    __syncthreads();
    #pragma unroll 4
    for (int i = 0; i < T_SEQ / 64; ++i) {
        const int t = i * 64 + lane;
        out[1 + t] = (float)path_lds[t];
    }
}

// ------------------------------------------------------------------- launch
extern "C" void kernel_launch(void* const* d_in, const int* in_sizes, int n_in,
                              void* d_out, int out_size, void* d_ws, size_t ws_size,
                              hipStream_t stream)
{
    (void)in_sizes; (void)n_in; (void)out_size; (void)ws_size;

    const int*   sentence = (const int*)  d_in[0];
    const float* emb      = (const float*)d_in[1];
    const float* Wih_f    = (const float*)d_in[2];
    const float* Whh_f    = (const float*)d_in[3];
    const float* bih_f    = (const float*)d_in[4];
    const float* bhh_f    = (const float*)d_in[5];
    const float* Wih_b    = (const float*)d_in[6];
    const float* Whh_b    = (const float*)d_in[7];
    const float* bih_b    = (const float*)d_in[8];
    const float* bhh_b    = (const float*)d_in[9];
    const float* W_out    = (const float*)d_in[10];
    const float* b_out    = (const float*)d_in[11];
    const float* trans    = (const float*)d_in[12];

    float* ws      = (float*)d_ws;
    float* xprojb  = ws;                                        // 8192*4096
    float* hseq    = ws + (size_t)T_SEQ * 4096;                 // 2*8192*512
    float* feats   = hseq + (size_t)2 * T_SEQ * HDIM;           // 8192*9
    unsigned long long* bpw = (unsigned long long*)(feats + (size_t)T_SEQ * 9);

    // re-poison the h exchange buffer every launch (graph replay safety)
    hipMemsetAsync(hseq, 0x7F, (size_t)2 * T_SEQ * HDIM * sizeof(float), stream);

    gemm_xproj<<<dim3(64, 32), 256, 0, stream>>>(
        sentence, emb, Wih_f, Wih_b, bih_f, bhh_f, bih_b, bhh_b, xprojb);

    lstm_scan<<<dim3(64), 256, 0, stream>>>(
        xprojb, Whh_f, Whh_b, hseq);

    feats_kernel<<<dim3((T_SEQ * 9 + 255) / 256), 256, 0, stream>>>(
        hseq, W_out, b_out, feats);

    viterbi_kernel<<<dim3(1), 64, 0, stream>>>(feats, trans, bpw, (float*)d_out);
}

// Round 7
// 20021.718 us; speedup vs baseline: 1.2346x; 1.2346x over previous
//
#include <hip/hip_runtime.h>
#include <hip/hip_bf16.h>

// BiLSTM(512/dir, T=8192) + linear(9) + Viterbi decode.
//  K1 gemm_xproj : 128x128 tile, 8x8 register blocking (VALU fp32; no fp32 MFMA on CDNA4)
//  K2 lstm_scan  : 64 persistent blocks (32/dir) x 256 threads (4 waves), single-stage:
//                  - wave wv polls ONLY chunk wv of h(t-1): 1 u64/lane (dedup'd, R2-level
//                    traffic; R6's 4x-redundant waterfall poll was the regression)
//                  - stage to shared LDS (double-buffered by step parity)
//                  - ONE raw s_barrier (lgkmcnt only; poll loads can dangle)
//                  - dot: 4 rows x 32 k per lane (8 ds_read_b128; 4 FMAs per h float)
//                  - butterfly over 16 k-lanes -> all 4 gate sums on one lane -> gates,
//                    c-state, pack, u64 agent-atomic store (no tearing)
//  K3 feats      : feats[t,n] = [h_f|h_b] @ W_out^T + b_out
//  K4 viterbi    : single wave; backpointers packed 4b x 9 into u64/step.
//
// ws layout (floats):
//   [0)                 xprojb   8192*4096            = 128 MB
//   [+8192*4096)        h_seq    2*8192*512           =  32 MB (poisoned 0x7F each launch)
//   [+2*8192*512)       feats    8192*9
//   [then]              bpw      8192 u64

#define T_SEQ   8192
#define EMB     512
#define HDIM    512
#define POISON64 0x7F7F7F7F7F7F7F7Full  // |h|<1 so never produced

#define ALOAD(p)  __hip_atomic_load((p), __ATOMIC_RELAXED, __HIP_MEMORY_SCOPE_AGENT)

// ---------------------------------------------------------------- K1: GEMM
__global__ __launch_bounds__(256) void gemm_xproj(
    const int* __restrict__ sentence, const float* __restrict__ emb,
    const float* __restrict__ Wih_f, const float* __restrict__ Wih_b,
    const float* __restrict__ bih_f, const float* __restrict__ bhh_f,
    const float* __restrict__ bih_b, const float* __restrict__ bhh_b,
    float* __restrict__ xprojb)
{
    __shared__ float As[16][132];      // [kk][row], pad to 132 floats
    __shared__ float Bs[16][132];
    __shared__ int   srow[128];

    const int tid = threadIdx.x;
    const int bm = blockIdx.x;          // 64 tiles of 128 t
    const int bn = blockIdx.y;          // 32 tiles of 128 j (0..15 fwd, 16..31 bwd)
    const int fwd = (bn < 16);
    const float* __restrict__ W = fwd ? Wih_f : Wih_b;
    const int jbase = bn * 128 - (fwd ? 0 : 2048);

    if (tid < 128) srow[tid] = sentence[bm * 128 + tid];
    __syncthreads();

    const int lkk = tid & 15;           // staging k index
    const int lr  = tid >> 4;           // staging row group (8 rows)
    int sr[8];
    #pragma unroll
    for (int i = 0; i < 8; ++i) sr[i] = srow[lr * 8 + i];
    const float* wbase = W + (size_t)(jbase + lr * 8) * EMB + lkk;

    const int tx = tid & 15, ty = tid >> 4;
    float acc[8][8] = {};

    for (int kb = 0; kb < 32; ++kb) {
        const int k0 = kb * 16;
        #pragma unroll
        for (int i = 0; i < 8; ++i) {
            As[lkk][lr * 8 + i] = emb[(size_t)sr[i] * EMB + k0 + lkk];
            Bs[lkk][lr * 8 + i] = wbase[(size_t)i * EMB + k0];
        }
        __syncthreads();
        #pragma unroll
        for (int kk = 0; kk < 16; ++kk) {
            const float4 a0 = *(const float4*)&As[kk][ty * 8];
            const float4 a1 = *(const float4*)&As[kk][ty * 8 + 4];
            const float4 b0 = *(const float4*)&Bs[kk][tx * 8];
            const float4 b1 = *(const float4*)&Bs[kk][tx * 8 + 4];
            const float av[8] = {a0.x,a0.y,a0.z,a0.w,a1.x,a1.y,a1.z,a1.w};
            const float bv[8] = {b0.x,b0.y,b0.z,b0.w,b1.x,b1.y,b1.z,b1.w};
            #pragma unroll
            for (int i = 0; i < 8; ++i)
                #pragma unroll
                for (int j = 0; j < 8; ++j)
                    acc[i][j] = fmaf(av[i], bv[j], acc[i][j]);
        }
        __syncthreads();
    }

    const float* b1p = fwd ? bih_f : bih_b;
    const float* b2p = fwd ? bhh_f : bhh_b;
    float bias[8];
    #pragma unroll
    for (int j = 0; j < 8; ++j) {
        const int jj = jbase + tx * 8 + j;
        bias[j] = b1p[jj] + b2p[jj];
    }
    #pragma unroll
    for (int i = 0; i < 8; ++i) {
        const int t = bm * 128 + ty * 8 + i;
        float4* dst = (float4*)&xprojb[(size_t)t * 4096 + bn * 128 + tx * 8];
        dst[0] = make_float4(acc[i][0] + bias[0], acc[i][1] + bias[1],
                             acc[i][2] + bias[2], acc[i][3] + bias[3]);
        dst[1] = make_float4(acc[i][4] + bias[4], acc[i][5] + bias[5],
                             acc[i][6] + bias[6], acc[i][7] + bias[7]);
    }
}

// ------------------------------------------------------------- K2: LSTM scan
__device__ __forceinline__ float fsig(float x) { return 1.0f / (1.0f + __expf(-x)); }
__device__ __forceinline__ float ftanh(float x) {
    const float e = __expf(-2.0f * fabsf(x));
    return copysignf((1.0f - e) / (1.0f + e), x);
}
__device__ __forceinline__ unsigned long long pack2(float a, float b) {
    return (unsigned long long)__float_as_uint(a) |
           ((unsigned long long)__float_as_uint(b) << 32);
}
__device__ __forceinline__ float2 unpack2(unsigned long long u) {
    return make_float2(__uint_as_float((unsigned)(u & 0xffffffffull)),
                       __uint_as_float((unsigned)(u >> 32)));
}

__global__ __launch_bounds__(256, 1) void lstm_scan(
    const float* __restrict__ xprojb,
    const float* __restrict__ Whh_f, const float* __restrict__ Whh_b,
    float* __restrict__ hseq)
{
    const int tid  = threadIdx.x;
    const int lane = tid & 63;
    const int wv   = tid >> 6;          // wave 0..3; polls chunk wv, owns h[.. wv*4 ..+4)
    const int blk  = blockIdx.x;        // 0..63
    const int dir  = blk & 1;
    const int sub  = blk >> 1;          // 0..31; block owns h[sub*16 .. sub*16+16)
    const float* __restrict__ Whh = dir ? Whh_b : Whh_f;
    float* hs = hseq + (size_t)dir * T_SEQ * HDIM;

    const int jm = lane >> 4;           // 0..3 : which h of this wave (m = wv*4+jm)
    const int ks = lane & 15;           // k-segment of 32 (k in [32ks, 32ks+32))
    const int m  = wv * 4 + jm;

    // weights: rows {g*512 + sub*16 + m, g=0..3} x k [32ks, 32ks+32)  -> 128 regs
    float wr[4][32];
    #pragma unroll
    for (int g = 0; g < 4; ++g) {
        const float* src = Whh + (size_t)(g * 512 + sub * 16 + m) * 512 + ks * 32;
        #pragma unroll
        for (int i = 0; i < 8; ++i) {
            const float4 v = *(const float4*)(src + 4 * i);
            wr[g][4*i] = v.x; wr[g][4*i+1] = v.y; wr[g][4*i+2] = v.z; wr[g][4*i+3] = v.w;
        }
    }

    // staged h, double-buffered by step parity: hsh[p][seg][36], seg = k/32
    __shared__ __align__(16) float hsh[2][16][36];

    const bool gl = (ks == 0);          // gate lanes: 0,16,32,48
    float c_state = 0.0f;

    #pragma unroll 1
    for (int s = 0; s < T_SEQ; ++s) {
        const int t = dir ? (T_SEQ - 1 - s) : s;
        const int p = s & 1;

        // xproj prefetch for gate lanes — issued before the poll, hides under it
        float xp0 = 0.f, xp1 = 0.f, xp2 = 0.f, xp3 = 0.f;
        if (gl) {
            const float* xr = xprojb + (size_t)t * 4096 + dir * 2048 + sub * 16 + m;
            xp0 = xr[0]; xp1 = xr[512]; xp2 = xr[1024]; xp3 = xr[1536];
        }

        // poll chunk wv: u64 index wv*64 + lane of h(t-1)
        float2 hv2;
        if (s == 0) {
            hv2 = make_float2(0.f, 0.f);
        } else {
            const int tprev = dir ? (t + 1) : (t - 1);
            const unsigned long long* hp =
                (const unsigned long long*)(hs + (size_t)tprev * HDIM) + wv * 64 + lane;
            unsigned long long u = ALOAD(hp);
            while (u == POISON64) u = ALOAD(hp);
            hv2 = unpack2(u);
        }
        // stage: floats [2*lane, 2*lane+1] of chunk wv -> seg wv*4+(lane>>4), pos 2*(lane&15)
        *(float2*)&hsh[p][wv * 4 + (lane >> 4)][2 * (lane & 15)] = hv2;

        // LDS-visible barrier WITHOUT vmcnt drain (keeps poll/xproj loads free)
        asm volatile("s_waitcnt lgkmcnt(0)\n\ts_barrier" ::: "memory");
        __builtin_amdgcn_sched_barrier(0);

        // dot: 4 gate-rows x 32 k per lane; reads seg ks (2-way bank alias = free)
        float a0 = 0.f, a1 = 0.f, a2 = 0.f, a3 = 0.f;
        const float4* h4 = (const float4*)&hsh[p][ks][0];
        #pragma unroll
        for (int i = 0; i < 8; ++i) {
            const float4 hv = h4[i];
            a0 = fmaf(wr[0][4*i],   hv.x, a0); a1 = fmaf(wr[1][4*i],   hv.x, a1);
            a2 = fmaf(wr[2][4*i],   hv.x, a2); a3 = fmaf(wr[3][4*i],   hv.x, a3);
            a0 = fmaf(wr[0][4*i+1], hv.y, a0); a1 = fmaf(wr[1][4*i+1], hv.y, a1);
            a2 = fmaf(wr[2][4*i+1], hv.y, a2); a3 = fmaf(wr[3][4*i+1], hv.y, a3);
            a0 = fmaf(wr[0][4*i+2], hv.z, a0); a1 = fmaf(wr[1][4*i+2], hv.z, a1);
            a2 = fmaf(wr[2][4*i+2], hv.z, a2); a3 = fmaf(wr[3][4*i+2], hv.z, a3);
            a0 = fmaf(wr[0][4*i+3], hv.w, a0); a1 = fmaf(wr[1][4*i+3], hv.w, a1);
            a2 = fmaf(wr[2][4*i+3], hv.w, a2); a3 = fmaf(wr[3][4*i+3], hv.w, a3);
        }
        // butterfly over the 16 k-lanes of this jm group
        #pragma unroll
        for (int d = 1; d <= 8; d <<= 1) {
            a0 += __shfl_xor(a0, d); a1 += __shfl_xor(a1, d);
            a2 += __shfl_xor(a2, d); a3 += __shfl_xor(a3, d);
        }

        float h = 0.f;
        if (gl) {
            const float i_ = fsig(a0 + xp0);
            const float f_ = fsig(a1 + xp1);
            const float g_ = ftanh(a2 + xp2);
            const float o_ = fsig(a3 + xp3);
            c_state = fmaf(f_, c_state, i_ * g_);
            h = o_ * ftanh(c_state);
        }
        // pack h pairs: h values live at lanes 0,16,32,48 (jm=0..3)
        const float ha = __shfl(h, (lane * 32) & 63);        // lane0<-0, lane1<-32
        const float hb = __shfl(h, (lane * 32 + 16) & 63);   // lane0<-16, lane1<-48
        if (lane < 2) {
            unsigned long long* hdst =
                (unsigned long long*)(hs + (size_t)t * HDIM + sub * 16 + wv * 4) ;
            __hip_atomic_store(hdst + lane, pack2(ha, hb), __ATOMIC_RELAXED,
                               __HIP_MEMORY_SCOPE_AGENT);
        }
    }
}

// ---------------------------------------------------------------- K3: feats
__global__ __launch_bounds__(256) void feats_kernel(
    const float* __restrict__ hseq, const float* __restrict__ W_out,
    const float* __restrict__ b_out, float* __restrict__ feats)
{
    const int idx = blockIdx.x * 256 + threadIdx.x;   // (t, n)
    if (idx >= T_SEQ * 9) return;
    const int t = idx / 9;
    const int n = idx - t * 9;
    const float4* hf = (const float4*)(hseq + (size_t)t * HDIM);
    const float4* hb = (const float4*)(hseq + (size_t)(T_SEQ + t) * HDIM);
    const float4* wf = (const float4*)(W_out + (size_t)n * 1024);
    const float4* wb = wf + 128;
    float acc = b_out[n];
    #pragma unroll 8
    for (int i = 0; i < 128; ++i) {
        const float4 a = hf[i], w = wf[i];
        acc = fmaf(a.x, w.x, acc); acc = fmaf(a.y, w.y, acc);
        acc = fmaf(a.z, w.z, acc); acc = fmaf(a.w, w.w, acc);
    }
    #pragma unroll 8
    for (int i = 0; i < 128; ++i) {
        const float4 a = hb[i], w = wb[i];
        acc = fmaf(a.x, w.x, acc); acc = fmaf(a.y, w.y, acc);
        acc = fmaf(a.z, w.z, acc); acc = fmaf(a.w, w.w, acc);
    }
    feats[idx] = acc;
}

// --------------------------------------------------------------- K4: viterbi
__global__ __launch_bounds__(64) void viterbi_kernel(
    const float* __restrict__ feats, const float* __restrict__ trans,
    unsigned long long* __restrict__ bpw, float* __restrict__ out)
{
    const int lane = threadIdx.x;
    __shared__ __align__(16) float flds[1024 * 9];
    __shared__ unsigned char path_lds[T_SEQ];

    float tr[9];
    #pragma unroll
    for (int p = 0; p < 9; ++p) tr[p] = 0.f;
    float tstop = 0.f;
    if (lane < 9) {
        #pragma unroll
        for (int p = 0; p < 9; ++p) tr[p] = trans[lane * 9 + p];
        tstop = trans[8 * 9 + lane];
    }
    float fv = (lane == 7) ? 0.0f : -10000.0f;        // START_IDX = 7

    for (int ch = 0; ch < 8; ++ch) {
        const float4* src = (const float4*)(feats + (size_t)ch * 9216);
        #pragma unroll
        for (int i = 0; i < 36; ++i)
            ((float4*)flds)[lane + i * 64] = src[lane + i * 64];
        __syncthreads();

        for (int tt = 0; tt < 1024; ++tt) {
            const int t = ch * 1024 + tt;
            const float f0 = __shfl(fv, 0), f1 = __shfl(fv, 1), f2 = __shfl(fv, 2);
            const float f3 = __shfl(fv, 3), f4 = __shfl(fv, 4), f5 = __shfl(fv, 5);
            const float f6 = __shfl(fv, 6), f7 = __shfl(fv, 7), f8 = __shfl(fv, 8);
            const float s0 = f0 + tr[0], s1 = f1 + tr[1], s2 = f2 + tr[2];
            const float s3 = f3 + tr[3], s4 = f4 + tr[4], s5 = f5 + tr[5];
            const float s6 = f6 + tr[6], s7 = f7 + tr[7], s8 = f8 + tr[8];
            const float mx = fmaxf(fmaxf(fmaxf(fmaxf(s0, s1), fmaxf(s2, s3)),
                                         fmaxf(fmaxf(s4, s5), fmaxf(s6, s7))), s8);
            const unsigned bits =
                (s0 >= mx ? 1u : 0u)   | (s1 >= mx ? 2u : 0u)   | (s2 >= mx ? 4u : 0u) |
                (s3 >= mx ? 8u : 0u)   | (s4 >= mx ? 16u : 0u)  | (s5 >= mx ? 32u : 0u) |
                (s6 >= mx ? 64u : 0u)  | (s7 >= mx ? 128u : 0u) | (s8 >= mx ? 256u : 0u);
            const int bi = __ffs(bits) - 1;
            const float feat = (lane < 9) ? flds[tt * 9 + lane] : 0.0f;
            fv = mx + feat;
            const unsigned long long b0 = __ballot(bi & 1);
            const unsigned long long b1 = __ballot(bi & 2);
            const unsigned long long b2 = __ballot(bi & 4);
            const unsigned long long b3 = __ballot(bi & 8);
            if (lane == 0) {
                bpw[t] = (b0 & 511ull) | ((b1 & 511ull) << 9) |
                         ((b2 & 511ull) << 18) | ((b3 & 511ull) << 27);
            }
        }
        __syncthreads();
    }

    const float term = fv + tstop;
    const float t0 = __shfl(term, 0), t1 = __shfl(term, 1), t2 = __shfl(term, 2);
    const float t3 = __shfl(term, 3), t4 = __shfl(term, 4), t5 = __shfl(term, 5);
    const float t6 = __shfl(term, 6), t7 = __shfl(term, 7), t8 = __shfl(term, 8);
    const float mxt = fmaxf(fmaxf(fmaxf(fmaxf(t0, t1), fmaxf(t2, t3)),
                                  fmaxf(fmaxf(t4, t5), fmaxf(t6, t7))), t8);
    const unsigned bitst =
        (t0 >= mxt ? 1u : 0u)   | (t1 >= mxt ? 2u : 0u)   | (t2 >= mxt ? 4u : 0u) |
        (t3 >= mxt ? 8u : 0u)   | (t4 >= mxt ? 16u : 0u)  | (t5 >= mxt ? 32u : 0u) |
        (t6 >= mxt ? 64u : 0u)  | (t7 >= mxt ? 128u : 0u) | (t8 >= mxt ? 256u : 0u);
    const int best = __ffs(bitst) - 1;

    if (lane == 0) {
        out[0] = mxt;
        int c = best;
        path_lds[T_SEQ - 1] = (unsigned char)c;
        for (int thi = T_SEQ - 2; thi >= 15; thi -= 16) {
            const int tlo = thi - 15;
            unsigned long long wbuf[16];
            #pragma unroll
            for (int i = 0; i < 16; ++i) wbuf[i] = bpw[tlo + 1 + i];
            #pragma unroll
            for (int i = 15; i >= 0; --i) {
                const unsigned long long wvv = wbuf[i];
                c = (int)((wvv >> c) & 1ull) |
                    ((int)((wvv >> (9 + c)) & 1ull) << 1) |
                    ((int)((wvv >> (18 + c)) & 1ull) << 2) |
                    ((int)((wvv >> (27 + c)) & 1ull) << 3);
                path_lds[tlo + i] = (unsigned char)c;
            }
        }
        for (int t2i = 14; t2i >= 0; --t2i) {
            const unsigned long long wvv = bpw[t2i + 1];
            c = (int)((wvv >> c) & 1ull) |
                ((int)((wvv >> (9 + c)) & 1ull) << 1) |
                ((int)((wvv >> (18 + c)) & 1ull) << 2) |
                ((int)((wvv >> (27 + c)) & 1ull) << 3);
            path_lds[t2i] = (unsigned char)c;
        }
    }
    __syncthreads();
    #pragma unroll 4
    for (int i = 0; i < T_SEQ / 64; ++i) {
        const int t = i * 64 + lane;
        out[1 + t] = (float)path_lds[t];
    }
}

// ------------------------------------------------------------------- launch
extern "C" void kernel_launch(void* const* d_in, const int* in_sizes, int n_in,
                              void* d_out, int out_size, void* d_ws, size_t ws_size,
                              hipStream_t stream)
{
    (void)in_sizes; (void)n_in; (void)out_size; (void)ws_size;

    const int*   sentence = (const int*)  d_in[0];
    const float* emb      = (const float*)d_in[1];
    const float* Wih_f    = (const float*)d_in[2];
    const float* Whh_f    = (const float*)d_in[3];
    const float* bih_f    = (const float*)d_in[4];
    const float* bhh_f    = (const float*)d_in[5];
    const float* Wih_b    = (const float*)d_in[6];
    const float* Whh_b    = (const float*)d_in[7];
    const float* bih_b    = (const float*)d_in[8];
    const float* bhh_b    = (const float*)d_in[9];
    const float* W_out    = (const float*)d_in[10];
    const float* b_out    = (const float*)d_in[11];
    const float* trans    = (const float*)d_in[12];

    float* ws      = (float*)d_ws;
    float* xprojb  = ws;                                        // 8192*4096
    float* hseq    = ws + (size_t)T_SEQ * 4096;                 // 2*8192*512
    float* feats   = hseq + (size_t)2 * T_SEQ * HDIM;           // 8192*9
    unsigned long long* bpw = (unsigned long long*)(feats + (size_t)T_SEQ * 9);

    // re-poison the h exchange buffer every launch (graph replay safety)
    hipMemsetAsync(hseq, 0x7F, (size_t)2 * T_SEQ * HDIM * sizeof(float), stream);

    gemm_xproj<<<dim3(64, 32), 256, 0, stream>>>(
        sentence, emb, Wih_f, Wih_b, bih_f, bhh_f, bih_b, bhh_b, xprojb);

    lstm_scan<<<dim3(64), 256, 0, stream>>>(
        xprojb, Whh_f, Whh_b, hseq);

    feats_kernel<<<dim3((T_SEQ * 9 + 255) / 256), 256, 0, stream>>>(
        hseq, W_out, b_out, feats);

    viterbi_kernel<<<dim3(1), 64, 0, stream>>>(feats, trans, bpw, (float*)d_out);
}

// Round 8
// 20011.510 us; speedup vs baseline: 1.2352x; 1.0005x over previous
//
#include <hip/hip_runtime.h>
#include <hip/hip_bf16.h>

// BiLSTM(512/dir, T=8192) + linear(9) + Viterbi decode.
//  K1 gemm_xproj : 128x128 tile, 8x8 register blocking (VALU fp32; no fp32 MFMA on CDNA4)
//  K2 lstm_scan  : 64 persistent blocks (32/dir) x 256 threads (4 waves), single-stage:
//                  - wave wv polls ONLY chunk wv of h(t-1): 1 u64/lane
//                  - h exchange via SYSTEM-scope atomics (write-through to MALL; avoids
//                    remote dirty-L2 snoop on cross-XCD polls — R7 used agent scope)
//                  - xproj prefetched ONE STEP AHEAD (full-step head start; poll's
//                    vmcnt drain no longer waits cold HBM loads)
//                  - stage to shared LDS (double-buffered), ONE raw s_barrier (lgkm only)
//                  - dot: 4 rows x 32 k per lane; butterfly over 16 k-lanes; gates,
//                    c-state, pack, u64 store
//  K3 feats      : feats[t,n] = [h_f|h_b] @ W_out^T + b_out
//  K4 viterbi    : single wave; backpointers packed 4b x 9 into u64/step.
//
// ws layout (floats):
//   [0)                 xprojb   8192*4096            = 128 MB
//   [+8192*4096)        h_seq    2*8192*512           =  32 MB (poisoned 0x7F each launch)
//   [+2*8192*512)       feats    8192*9
//   [then]              bpw      8192 u64

#define T_SEQ   8192
#define EMB     512
#define HDIM    512
#define POISON64 0x7F7F7F7F7F7F7F7Full  // |h|<1 so never produced

#define ALOAD_SYS(p)     __hip_atomic_load((p), __ATOMIC_RELAXED, __HIP_MEMORY_SCOPE_SYSTEM)
#define ASTORE_SYS(p, v) __hip_atomic_store((p), (v), __ATOMIC_RELAXED, __HIP_MEMORY_SCOPE_SYSTEM)

// ---------------------------------------------------------------- K1: GEMM
__global__ __launch_bounds__(256) void gemm_xproj(
    const int* __restrict__ sentence, const float* __restrict__ emb,
    const float* __restrict__ Wih_f, const float* __restrict__ Wih_b,
    const float* __restrict__ bih_f, const float* __restrict__ bhh_f,
    const float* __restrict__ bih_b, const float* __restrict__ bhh_b,
    float* __restrict__ xprojb)
{
    __shared__ float As[16][132];      // [kk][row], pad to 132 floats
    __shared__ float Bs[16][132];
    __shared__ int   srow[128];

    const int tid = threadIdx.x;
    const int bm = blockIdx.x;          // 64 tiles of 128 t
    const int bn = blockIdx.y;          // 32 tiles of 128 j (0..15 fwd, 16..31 bwd)
    const int fwd = (bn < 16);
    const float* __restrict__ W = fwd ? Wih_f : Wih_b;
    const int jbase = bn * 128 - (fwd ? 0 : 2048);

    if (tid < 128) srow[tid] = sentence[bm * 128 + tid];
    __syncthreads();

    const int lkk = tid & 15;           // staging k index
    const int lr  = tid >> 4;           // staging row group (8 rows)
    int sr[8];
    #pragma unroll
    for (int i = 0; i < 8; ++i) sr[i] = srow[lr * 8 + i];
    const float* wbase = W + (size_t)(jbase + lr * 8) * EMB + lkk;

    const int tx = tid & 15, ty = tid >> 4;
    float acc[8][8] = {};

    for (int kb = 0; kb < 32; ++kb) {
        const int k0 = kb * 16;
        #pragma unroll
        for (int i = 0; i < 8; ++i) {
            As[lkk][lr * 8 + i] = emb[(size_t)sr[i] * EMB + k0 + lkk];
            Bs[lkk][lr * 8 + i] = wbase[(size_t)i * EMB + k0];
        }
        __syncthreads();
        #pragma unroll
        for (int kk = 0; kk < 16; ++kk) {
            const float4 a0 = *(const float4*)&As[kk][ty * 8];
            const float4 a1 = *(const float4*)&As[kk][ty * 8 + 4];
            const float4 b0 = *(const float4*)&Bs[kk][tx * 8];
            const float4 b1 = *(const float4*)&Bs[kk][tx * 8 + 4];
            const float av[8] = {a0.x,a0.y,a0.z,a0.w,a1.x,a1.y,a1.z,a1.w};
            const float bv[8] = {b0.x,b0.y,b0.z,b0.w,b1.x,b1.y,b1.z,b1.w};
            #pragma unroll
            for (int i = 0; i < 8; ++i)
                #pragma unroll
                for (int j = 0; j < 8; ++j)
                    acc[i][j] = fmaf(av[i], bv[j], acc[i][j]);
        }
        __syncthreads();
    }

    const float* b1p = fwd ? bih_f : bih_b;
    const float* b2p = fwd ? bhh_f : bhh_b;
    float bias[8];
    #pragma unroll
    for (int j = 0; j < 8; ++j) {
        const int jj = jbase + tx * 8 + j;
        bias[j] = b1p[jj] + b2p[jj];
    }
    #pragma unroll
    for (int i = 0; i < 8; ++i) {
        const int t = bm * 128 + ty * 8 + i;
        float4* dst = (float4*)&xprojb[(size_t)t * 4096 + bn * 128 + tx * 8];
        dst[0] = make_float4(acc[i][0] + bias[0], acc[i][1] + bias[1],
                             acc[i][2] + bias[2], acc[i][3] + bias[3]);
        dst[1] = make_float4(acc[i][4] + bias[4], acc[i][5] + bias[5],
                             acc[i][6] + bias[6], acc[i][7] + bias[7]);
    }
}

// ------------------------------------------------------------- K2: LSTM scan
__device__ __forceinline__ float fsig(float x) { return 1.0f / (1.0f + __expf(-x)); }
__device__ __forceinline__ float ftanh(float x) {
    const float e = __expf(-2.0f * fabsf(x));
    return copysignf((1.0f - e) / (1.0f + e), x);
}
__device__ __forceinline__ unsigned long long pack2(float a, float b) {
    return (unsigned long long)__float_as_uint(a) |
           ((unsigned long long)__float_as_uint(b) << 32);
}
__device__ __forceinline__ float2 unpack2(unsigned long long u) {
    return make_float2(__uint_as_float((unsigned)(u & 0xffffffffull)),
                       __uint_as_float((unsigned)(u >> 32)));
}

__global__ __launch_bounds__(256, 1) void lstm_scan(
    const float* __restrict__ xprojb,
    const float* __restrict__ Whh_f, const float* __restrict__ Whh_b,
    float* __restrict__ hseq)
{
    const int tid  = threadIdx.x;
    const int lane = tid & 63;
    const int wv   = tid >> 6;          // wave 0..3; polls chunk wv, owns h[.. wv*4 ..+4)
    const int blk  = blockIdx.x;        // 0..63
    const int dir  = blk & 1;
    const int sub  = blk >> 1;          // 0..31; block owns h[sub*16 .. sub*16+16)
    const float* __restrict__ Whh = dir ? Whh_b : Whh_f;
    float* hs = hseq + (size_t)dir * T_SEQ * HDIM;

    const int jm = lane >> 4;           // 0..3 : which h of this wave (m = wv*4+jm)
    const int ks = lane & 15;           // k-segment of 32 (k in [32ks, 32ks+32))
    const int m  = wv * 4 + jm;

    // weights: rows {g*512 + sub*16 + m, g=0..3} x k [32ks, 32ks+32)  -> 128 regs
    float wr[4][32];
    #pragma unroll
    for (int g = 0; g < 4; ++g) {
        const float* src = Whh + (size_t)(g * 512 + sub * 16 + m) * 512 + ks * 32;
        #pragma unroll
        for (int i = 0; i < 8; ++i) {
            const float4 v = *(const float4*)(src + 4 * i);
            wr[g][4*i] = v.x; wr[g][4*i+1] = v.y; wr[g][4*i+2] = v.z; wr[g][4*i+3] = v.w;
        }
    }

    // staged h, double-buffered by step parity: hsh[p][seg][36], seg = k/32
    __shared__ __align__(16) float hsh[2][16][36];

    const bool gl = (ks == 0);          // gate lanes: 0,16,32,48
    const float* xrbase = xprojb + (size_t)dir * 2048 + sub * 16 + m;
    float c_state = 0.0f;

    // xproj prefetch for step 0 (full head start before the loop's first use)
    float xp0 = 0.f, xp1 = 0.f, xp2 = 0.f, xp3 = 0.f;
    if (gl) {
        const int t0 = dir ? (T_SEQ - 1) : 0;
        const float* xr = xrbase + (size_t)t0 * 4096;
        xp0 = xr[0]; xp1 = xr[512]; xp2 = xr[1024]; xp3 = xr[1536];
    }

    #pragma unroll 1
    for (int s = 0; s < T_SEQ; ++s) {
        const int t = dir ? (T_SEQ - 1 - s) : s;
        const int p = s & 1;

        // poll chunk wv: u64 index wv*64 + lane of h(t-1); SYSTEM scope
        float2 hv2;
        if (s == 0) {
            hv2 = make_float2(0.f, 0.f);
        } else {
            const int tprev = dir ? (t + 1) : (t - 1);
            const unsigned long long* hp =
                (const unsigned long long*)(hs + (size_t)tprev * HDIM) + wv * 64 + lane;
            unsigned long long u = ALOAD_SYS(hp);
            while (u == POISON64) u = ALOAD_SYS(hp);
            hv2 = unpack2(u);
        }
        // stage: floats [2*lane, 2*lane+1] of chunk wv -> seg wv*4+(lane>>4), pos 2*(lane&15)
        *(float2*)&hsh[p][wv * 4 + (lane >> 4)][2 * (lane & 15)] = hv2;

        // LDS-visible barrier WITHOUT vmcnt drain (keeps in-flight loads free)
        asm volatile("s_waitcnt lgkmcnt(0)\n\ts_barrier" ::: "memory");
        __builtin_amdgcn_sched_barrier(0);

        // dot: 4 gate-rows x 32 k per lane; reads seg ks (2-way bank alias = free)
        float a0 = 0.f, a1 = 0.f, a2 = 0.f, a3 = 0.f;
        const float4* h4 = (const float4*)&hsh[p][ks][0];
        #pragma unroll
        for (int i = 0; i < 8; ++i) {
            const float4 hv = h4[i];
            a0 = fmaf(wr[0][4*i],   hv.x, a0); a1 = fmaf(wr[1][4*i],   hv.x, a1);
            a2 = fmaf(wr[2][4*i],   hv.x, a2); a3 = fmaf(wr[3][4*i],   hv.x, a3);
            a0 = fmaf(wr[0][4*i+1], hv.y, a0); a1 = fmaf(wr[1][4*i+1], hv.y, a1);
            a2 = fmaf(wr[2][4*i+1], hv.y, a2); a3 = fmaf(wr[3][4*i+1], hv.y, a3);
            a0 = fmaf(wr[0][4*i+2], hv.z, a0); a1 = fmaf(wr[1][4*i+2], hv.z, a1);
            a2 = fmaf(wr[2][4*i+2], hv.z, a2); a3 = fmaf(wr[3][4*i+2], hv.z, a3);
            a0 = fmaf(wr[0][4*i+3], hv.w, a0); a1 = fmaf(wr[1][4*i+3], hv.w, a1);
            a2 = fmaf(wr[2][4*i+3], hv.w, a2); a3 = fmaf(wr[3][4*i+3], hv.w, a3);
        }
        // butterfly over the 16 k-lanes of this jm group
        #pragma unroll
        for (int d = 1; d <= 8; d <<= 1) {
            a0 += __shfl_xor(a0, d); a1 += __shfl_xor(a1, d);
            a2 += __shfl_xor(a2, d); a3 += __shfl_xor(a3, d);
        }

        float h = 0.f;
        if (gl) {
            const float i_ = fsig(a0 + xp0);
            const float f_ = fsig(a1 + xp1);
            const float g_ = ftanh(a2 + xp2);
            const float o_ = fsig(a3 + xp3);
            c_state = fmaf(f_, c_state, i_ * g_);
            h = o_ * ftanh(c_state);
        }
        // pack h pairs: h values live at lanes 0,16,32,48 (jm=0..3)
        const float ha = __shfl(h, (lane * 32) & 63);        // lane0<-0, lane1<-32
        const float hb = __shfl(h, (lane * 32 + 16) & 63);   // lane0<-16, lane1<-48
        if (lane < 2) {
            unsigned long long* hdst =
                (unsigned long long*)(hs + (size_t)t * HDIM + sub * 16 + wv * 4);
            ASTORE_SYS(hdst + lane, pack2(ha, hb));
        }

        // prefetch xproj for step s+1 — a full step of head start, so the next
        // poll's vmcnt drain never waits on cold HBM
        if (gl && s + 1 < T_SEQ) {
            const int tn = dir ? (t - 1) : (t + 1);
            const float* xr = xrbase + (size_t)tn * 4096;
            xp0 = xr[0]; xp1 = xr[512]; xp2 = xr[1024]; xp3 = xr[1536];
        }
    }
}

// ---------------------------------------------------------------- K3: feats
__global__ __launch_bounds__(256) void feats_kernel(
    const float* __restrict__ hseq, const float* __restrict__ W_out,
    const float* __restrict__ b_out, float* __restrict__ feats)
{
    const int idx = blockIdx.x * 256 + threadIdx.x;   // (t, n)
    if (idx >= T_SEQ * 9) return;
    const int t = idx / 9;
    const int n = idx - t * 9;
    const float4* hf = (const float4*)(hseq + (size_t)t * HDIM);
    const float4* hb = (const float4*)(hseq + (size_t)(T_SEQ + t) * HDIM);
    const float4* wf = (const float4*)(W_out + (size_t)n * 1024);
    const float4* wb = wf + 128;
    float acc = b_out[n];
    #pragma unroll 8
    for (int i = 0; i < 128; ++i) {
        const float4 a = hf[i], w = wf[i];
        acc = fmaf(a.x, w.x, acc); acc = fmaf(a.y, w.y, acc);
        acc = fmaf(a.z, w.z, acc); acc = fmaf(a.w, w.w, acc);
    }
    #pragma unroll 8
    for (int i = 0; i < 128; ++i) {
        const float4 a = hb[i], w = wb[i];
        acc = fmaf(a.x, w.x, acc); acc = fmaf(a.y, w.y, acc);
        acc = fmaf(a.z, w.z, acc); acc = fmaf(a.w, w.w, acc);
    }
    feats[idx] = acc;
}

// --------------------------------------------------------------- K4: viterbi
__global__ __launch_bounds__(64) void viterbi_kernel(
    const float* __restrict__ feats, const float* __restrict__ trans,
    unsigned long long* __restrict__ bpw, float* __restrict__ out)
{
    const int lane = threadIdx.x;
    __shared__ __align__(16) float flds[1024 * 9];
    __shared__ unsigned char path_lds[T_SEQ];

    float tr[9];
    #pragma unroll
    for (int p = 0; p < 9; ++p) tr[p] = 0.f;
    float tstop = 0.f;
    if (lane < 9) {
        #pragma unroll
        for (int p = 0; p < 9; ++p) tr[p] = trans[lane * 9 + p];
        tstop = trans[8 * 9 + lane];
    }
    float fv = (lane == 7) ? 0.0f : -10000.0f;        // START_IDX = 7

    for (int ch = 0; ch < 8; ++ch) {
        const float4* src = (const float4*)(feats + (size_t)ch * 9216);
        #pragma unroll
        for (int i = 0; i < 36; ++i)
            ((float4*)flds)[lane + i * 64] = src[lane + i * 64];
        __syncthreads();

        for (int tt = 0; tt < 1024; ++tt) {
            const int t = ch * 1024 + tt;
            const float f0 = __shfl(fv, 0), f1 = __shfl(fv, 1), f2 = __shfl(fv, 2);
            const float f3 = __shfl(fv, 3), f4 = __shfl(fv, 4), f5 = __shfl(fv, 5);
            const float f6 = __shfl(fv, 6), f7 = __shfl(fv, 7), f8 = __shfl(fv, 8);
            const float s0 = f0 + tr[0], s1 = f1 + tr[1], s2 = f2 + tr[2];
            const float s3 = f3 + tr[3], s4 = f4 + tr[4], s5 = f5 + tr[5];
            const float s6 = f6 + tr[6], s7 = f7 + tr[7], s8 = f8 + tr[8];
            const float mx = fmaxf(fmaxf(fmaxf(fmaxf(s0, s1), fmaxf(s2, s3)),
                                         fmaxf(fmaxf(s4, s5), fmaxf(s6, s7))), s8);
            const unsigned bits =
                (s0 >= mx ? 1u : 0u)   | (s1 >= mx ? 2u : 0u)   | (s2 >= mx ? 4u : 0u) |
                (s3 >= mx ? 8u : 0u)   | (s4 >= mx ? 16u : 0u)  | (s5 >= mx ? 32u : 0u) |
                (s6 >= mx ? 64u : 0u)  | (s7 >= mx ? 128u : 0u) | (s8 >= mx ? 256u : 0u);
            const int bi = __ffs(bits) - 1;
            const float feat = (lane < 9) ? flds[tt * 9 + lane] : 0.0f;
            fv = mx + feat;
            const unsigned long long b0 = __ballot(bi & 1);
            const unsigned long long b1 = __ballot(bi & 2);
            const unsigned long long b2 = __ballot(bi & 4);
            const unsigned long long b3 = __ballot(bi & 8);
            if (lane == 0) {
                bpw[t] = (b0 & 511ull) | ((b1 & 511ull) << 9) |
                         ((b2 & 511ull) << 18) | ((b3 & 511ull) << 27);
            }
        }
        __syncthreads();
    }

    const float term = fv + tstop;
    const float t0 = __shfl(term, 0), t1 = __shfl(term, 1), t2 = __shfl(term, 2);
    const float t3 = __shfl(term, 3), t4 = __shfl(term, 4), t5 = __shfl(term, 5);
    const float t6 = __shfl(term, 6), t7 = __shfl(term, 7), t8 = __shfl(term, 8);
    const float mxt = fmaxf(fmaxf(fmaxf(fmaxf(t0, t1), fmaxf(t2, t3)),
                                  fmaxf(fmaxf(t4, t5), fmaxf(t6, t7))), t8);
    const unsigned bitst =
        (t0 >= mxt ? 1u : 0u)   | (t1 >= mxt ? 2u : 0u)   | (t2 >= mxt ? 4u : 0u) |
        (t3 >= mxt ? 8u : 0u)   | (t4 >= mxt ? 16u : 0u)  | (t5 >= mxt ? 32u : 0u) |
        (t6 >= mxt ? 64u : 0u)  | (t7 >= mxt ? 128u : 0u) | (t8 >= mxt ? 256u : 0u);
    const int best = __ffs(bitst) - 1;

    if (lane == 0) {
        out[0] = mxt;
        int c = best;
        path_lds[T_SEQ - 1] = (unsigned char)c;
        for (int thi = T_SEQ - 2; thi >= 15; thi -= 16) {
            const int tlo = thi - 15;
            unsigned long long wbuf[16];
            #pragma unroll
            for (int i = 0; i < 16; ++i) wbuf[i] = bpw[tlo + 1 + i];
            #pragma unroll
            for (int i = 15; i >= 0; --i) {
                const unsigned long long wvv = wbuf[i];
                c = (int)((wvv >> c) & 1ull) |
                    ((int)((wvv >> (9 + c)) & 1ull) << 1) |
                    ((int)((wvv >> (18 + c)) & 1ull) << 2) |
                    ((int)((wvv >> (27 + c)) & 1ull) << 3);
                path_lds[tlo + i] = (unsigned char)c;
            }
        }
        for (int t2i = 14; t2i >= 0; --t2i) {
            const unsigned long long wvv = bpw[t2i + 1];
            c = (int)((wvv >> c) & 1ull) |
                ((int)((wvv >> (9 + c)) & 1ull) << 1) |
                ((int)((wvv >> (18 + c)) & 1ull) << 2) |
                ((int)((wvv >> (27 + c)) & 1ull) << 3);
            path_lds[t2i] = (unsigned char)c;
        }
    }
    __syncthreads();
    #pragma unroll 4
    for (int i = 0; i < T_SEQ / 64; ++i) {
        const int t = i * 64 + lane;
        out[1 + t] = (float)path_lds[t];
    }
}

// ------------------------------------------------------------------- launch
extern "C" void kernel_launch(void* const* d_in, const int* in_sizes, int n_in,
                              void* d_out, int out_size, void* d_ws, size_t ws_size,
                              hipStream_t stream)
{
    (void)in_sizes; (void)n_in; (void)out_size; (void)ws_size;

    const int*   sentence = (const int*)  d_in[0];
    const float* emb      = (const float*)d_in[1];
    const float* Wih_f    = (const float*)d_in[2];
    const float* Whh_f    = (const float*)d_in[3];
    const float* bih_f    = (const float*)d_in[4];
    const float* bhh_f    = (const float*)d_in[5];
    const float* Wih_b    = (const float*)d_in[6];
    const float* Whh_b    = (const float*)d_in[7];
    const float* bih_b    = (const float*)d_in[8];
    const float* bhh_b    = (const float*)d_in[9];
    const float* W_out    = (const float*)d_in[10];
    const float* b_out    = (const float*)d_in[11];
    const float* trans    = (const float*)d_in[12];

    float* ws      = (float*)d_ws;
    float* xprojb  = ws;                                        // 8192*4096
    float* hseq    = ws + (size_t)T_SEQ * 4096;                 // 2*8192*512
    float* feats   = hseq + (size_t)2 * T_SEQ * HDIM;           // 8192*9
    unsigned long long* bpw = (unsigned long long*)(feats + (size_t)T_SEQ * 9);

    // re-poison the h exchange buffer every launch (graph replay safety)
    hipMemsetAsync(hseq, 0x7F, (size_t)2 * T_SEQ * HDIM * sizeof(float), stream);

    gemm_xproj<<<dim3(64, 32), 256, 0, stream>>>(
        sentence, emb, Wih_f, Wih_b, bih_f, bhh_f, bih_b, bhh_b, xprojb);

    lstm_scan<<<dim3(64), 256, 0, stream>>>(
        xprojb, Whh_f, Whh_b, hseq);

    feats_kernel<<<dim3((T_SEQ * 9 + 255) / 256), 256, 0, stream>>>(
        hseq, W_out, b_out, feats);

    viterbi_kernel<<<dim3(1), 64, 0, stream>>>(feats, trans, bpw, (float*)d_out);
}